// Round 3
// baseline (1104.736 us; speedup 1.0000x reference)
//
#include <hip/hip_runtime.h>
#include <math.h>

#define N_NODES 50000
#define N_EDGES 400000
#define N_E_TOT (N_EDGES + N_NODES)   // + self loops = 450000
#define HEADS 4
#define CH 128
#define HC 512                        // HEADS*CH
#define NEG_SLOPE 0.2f

// NOTE: harness converts integer inputs to int32 ("integer -> const int*").
// Reading as int64 overruns the buffer (round-2 crash).

// ---------------- K1: h = x @ W  (x [N,128], W [128,512] -> h [N,512]) ----------------
// 256 threads/block, 32 rows/block; each thread computes 16 rows x 4 cols
// (2 row-halves x 128 col-groups x 4 cols = full 32x512 tile).
__global__ __launch_bounds__(256) void k_gemm(const float* __restrict__ x,
                                              const float* __restrict__ W,
                                              float* __restrict__ h) {
    __shared__ float xs[32][128];
    const int r0  = blockIdx.x * 32;
    const int tid = threadIdx.x;

    // stage x tile (32x128 floats = 1024 float4)
    {
        const float4* x4 = (const float4*)x;
        float4* xs4 = (float4*)&xs[0][0];
#pragma unroll
        for (int i = 0; i < 4; ++i) {
            int idx  = tid + 256 * i;      // float4 index in tile
            int row  = idx >> 5;           // 32 float4 per row
            int col4 = idx & 31;
            int grow = r0 + row;
            float4 v;
            if (grow < N_NODES) v = x4[grow * 32 + col4];
            else { v.x = v.y = v.z = v.w = 0.f; }
            xs4[idx] = v;
        }
    }
    __syncthreads();

    const int ty = tid >> 7;     // row half (0/1): rows ty*16 .. ty*16+15
    const int tx = tid & 127;    // col group
    const int c0 = tx * 4;       // covers all 512 cols

    float acc[16][4];
#pragma unroll
    for (int r = 0; r < 16; ++r)
#pragma unroll
        for (int c = 0; c < 4; ++c) acc[r][c] = 0.f;

    for (int k = 0; k < 128; k += 4) {
        float4 w[4];
#pragma unroll
        for (int kk = 0; kk < 4; ++kk)
            w[kk] = *(const float4*)&W[(k + kk) * HC + c0];
#pragma unroll
        for (int r = 0; r < 16; ++r) {
            float4 xv = *(const float4*)&xs[ty * 16 + r][k];   // wave-uniform broadcast
            acc[r][0] += xv.x * w[0].x + xv.y * w[1].x + xv.z * w[2].x + xv.w * w[3].x;
            acc[r][1] += xv.x * w[0].y + xv.y * w[1].y + xv.z * w[2].y + xv.w * w[3].y;
            acc[r][2] += xv.x * w[0].z + xv.y * w[1].z + xv.z * w[2].z + xv.w * w[3].z;
            acc[r][3] += xv.x * w[0].w + xv.y * w[1].w + xv.z * w[2].w + xv.w * w[3].w;
        }
    }

#pragma unroll
    for (int r = 0; r < 16; ++r) {
        int grow = r0 + ty * 16 + r;
        if (grow < N_NODES) {
            float4 o; o.x = acc[r][0]; o.y = acc[r][1]; o.z = acc[r][2]; o.w = acc[r][3];
            *(float4*)&h[(size_t)grow * HC + c0] = o;
        }
    }
}

// ---------------- K2: a_src[n,h] = sum_c h[n,h,c]*att_src[h,c]; same for a_dst ----------------
__global__ __launch_bounds__(512) void k_att(const float* __restrict__ h,
                                             const float* __restrict__ att_src,
                                             const float* __restrict__ att_dst,
                                             float* __restrict__ a_src,
                                             float* __restrict__ a_dst) {
    __shared__ float ss[512];
    __shared__ float sd[512];
    const int n = blockIdx.x;
    const int t = threadIdx.x;
    float v  = h[(size_t)n * HC + t];
    ss[t] = v * att_src[t];
    sd[t] = v * att_dst[t];
    __syncthreads();
    if ((t & 127) < 64) { ss[t] += ss[t + 64]; sd[t] += sd[t + 64]; }
    __syncthreads();
    float s2 = ss[t], d2 = sd[t];
#pragma unroll
    for (int off = 32; off > 0; off >>= 1) {
        s2 += __shfl_down(s2, off);
        d2 += __shfl_down(d2, off);
    }
    if ((t & 127) == 0) {                 // first lane of the first wave of each head-group
        int g = t >> 7;
        a_src[n * HEADS + g] = s2;
        a_dst[n * HEADS + g] = d2;
    }
}

// ---------------- K3: out[n,:] = bias (atomic accumulation target) ----------------
__global__ void k_init_out(float* __restrict__ out, const float* __restrict__ bias) {
    int idx4 = blockIdx.x * blockDim.x + threadIdx.x;       // float4 index
    if (idx4 >= N_NODES * HC / 4) return;
    int col4 = idx4 & (HC / 4 - 1);
    ((float4*)out)[idx4] = ((const float4*)bias)[col4];
}

// ---------------- K4: e_exp + denom (softmax without max-shift; e bounded ~8) ----------------
__global__ void k_edge1(const int* __restrict__ ei,
                        const float* __restrict__ a_src,
                        const float* __restrict__ a_dst,
                        float* __restrict__ e_exp,
                        float* __restrict__ denom) {
    int e = blockIdx.x * blockDim.x + threadIdx.x;
    if (e >= N_E_TOT) return;
    int s, d;
    if (e < N_EDGES) { s = ei[e]; d = ei[N_EDGES + e]; }
    else             { s = d = e - N_EDGES; }
#pragma unroll
    for (int hh = 0; hh < HEADS; ++hh) {
        float v = a_src[s * HEADS + hh] + a_dst[d * HEADS + hh];
        v = v > 0.f ? v : NEG_SLOPE * v;
        float ex = expf(v);
        e_exp[e * HEADS + hh] = ex;
        atomicAdd(&denom[d * HEADS + hh], ex);
    }
}

// ---------------- K5: scatter messages, one wave per edge ----------------
__global__ __launch_bounds__(256) void k_edge2(const int* __restrict__ ei,
                                               const float* __restrict__ h,
                                               const float* __restrict__ e_exp,
                                               const float* __restrict__ denom,
                                               float* __restrict__ out) {
    int gtid = blockIdx.x * 256 + threadIdx.x;
    int e    = gtid >> 6;
    int lane = threadIdx.x & 63;
    if (e >= N_E_TOT) return;
    int s, d;
    if (e < N_EDGES) { s = ei[e]; d = ei[N_EDGES + e]; }
    else             { s = d = e - N_EDGES; }
    float alpha[HEADS];
#pragma unroll
    for (int hh = 0; hh < HEADS; ++hh)
        alpha[hh] = e_exp[e * HEADS + hh] / denom[d * HEADS + hh];
    const float* hs = h   + (size_t)s * HC;
    float*       od = out + (size_t)d * HC;
#pragma unroll
    for (int j = 0; j < 8; ++j) {
        int c = lane + 64 * j;
        atomicAdd(&od[c], alpha[j >> 1] * hs[c]);
    }
}

extern "C" void kernel_launch(void* const* d_in, const int* in_sizes, int n_in,
                              void* d_out, int out_size, void* d_ws, size_t ws_size,
                              hipStream_t stream) {
    const float* x       = (const float*)d_in[0];
    const int*   ei      = (const int*)  d_in[1];
    const float* W       = (const float*)d_in[2];
    const float* att_src = (const float*)d_in[3];
    const float* att_dst = (const float*)d_in[4];
    const float* bias    = (const float*)d_in[5];
    float* out = (float*)d_out;

    float* ws     = (float*)d_ws;
    float* h      = ws;                                   // N*512  = 25,600,000 f
    float* a_src  = h     + (size_t)N_NODES * HC;         // N*4
    float* a_dst  = a_src + N_NODES * HEADS;              // N*4
    float* denom  = a_dst + N_NODES * HEADS;              // N*4
    float* e_exp  = denom + N_NODES * HEADS;              // E'*4 = 1,800,000 f

    hipMemsetAsync(denom, 0, (size_t)N_NODES * HEADS * sizeof(float), stream);

    k_gemm<<<(N_NODES + 31) / 32, 256, 0, stream>>>(x, W, h);
    k_att<<<N_NODES, 512, 0, stream>>>(h, att_src, att_dst, a_src, a_dst);
    k_init_out<<<(N_NODES * HC / 4 + 255) / 256, 256, 0, stream>>>(out, bias);
    k_edge1<<<(N_E_TOT + 255) / 256, 256, 0, stream>>>(ei, a_src, a_dst, e_exp, denom);
    k_edge2<<<((size_t)N_E_TOT * 64 + 255) / 256, 256, 0, stream>>>(ei, h, e_exp, denom, out);
}

// Round 4
// 569.676 us; speedup vs baseline: 1.9392x; 1.9392x over previous
//
#include <hip/hip_runtime.h>
#include <math.h>

#define N_NODES 50000
#define N_EDGES 400000
#define HEADS 4
#define CH 128
#define HC 512                        // HEADS*CH
#define NEG_SLOPE 0.2f

// ---------------- K1: h = x @ W  (x [N,128], W [128,512] -> h [N,512]) ----------------
// 256 threads/block, 32 rows/block; each thread computes 16 rows x 4 cols.
__global__ __launch_bounds__(256) void k_gemm(const float* __restrict__ x,
                                              const float* __restrict__ W,
                                              float* __restrict__ h) {
    __shared__ float xs[32][128];
    const int r0  = blockIdx.x * 32;
    const int tid = threadIdx.x;

    {
        const float4* x4 = (const float4*)x;
        float4* xs4 = (float4*)&xs[0][0];
#pragma unroll
        for (int i = 0; i < 4; ++i) {
            int idx  = tid + 256 * i;
            int row  = idx >> 5;
            int col4 = idx & 31;
            int grow = r0 + row;
            float4 v;
            if (grow < N_NODES) v = x4[grow * 32 + col4];
            else { v.x = v.y = v.z = v.w = 0.f; }
            xs4[idx] = v;
        }
    }
    __syncthreads();

    const int ty = tid >> 7;
    const int tx = tid & 127;
    const int c0 = tx * 4;

    float acc[16][4];
#pragma unroll
    for (int r = 0; r < 16; ++r)
#pragma unroll
        for (int c = 0; c < 4; ++c) acc[r][c] = 0.f;

    for (int k = 0; k < 128; k += 4) {
        float4 w[4];
#pragma unroll
        for (int kk = 0; kk < 4; ++kk)
            w[kk] = *(const float4*)&W[(k + kk) * HC + c0];
#pragma unroll
        for (int r = 0; r < 16; ++r) {
            float4 xv = *(const float4*)&xs[ty * 16 + r][k];
            acc[r][0] += xv.x * w[0].x + xv.y * w[1].x + xv.z * w[2].x + xv.w * w[3].x;
            acc[r][1] += xv.x * w[0].y + xv.y * w[1].y + xv.z * w[2].y + xv.w * w[3].y;
            acc[r][2] += xv.x * w[0].z + xv.y * w[1].z + xv.z * w[2].z + xv.w * w[3].z;
            acc[r][3] += xv.x * w[0].w + xv.y * w[1].w + xv.z * w[2].w + xv.w * w[3].w;
        }
    }

#pragma unroll
    for (int r = 0; r < 16; ++r) {
        int grow = r0 + ty * 16 + r;
        if (grow < N_NODES) {
            float4 o; o.x = acc[r][0]; o.y = acc[r][1]; o.z = acc[r][2]; o.w = acc[r][3];
            *(float4*)&h[(size_t)grow * HC + c0] = o;
        }
    }
}

// ---------------- K2: a_src/a_dst = <h, att> per (node, head) ----------------
__global__ __launch_bounds__(512) void k_att(const float* __restrict__ h,
                                             const float* __restrict__ att_src,
                                             const float* __restrict__ att_dst,
                                             float* __restrict__ a_src,
                                             float* __restrict__ a_dst) {
    __shared__ float ss[512];
    __shared__ float sd[512];
    const int n = blockIdx.x;
    const int t = threadIdx.x;
    float v  = h[(size_t)n * HC + t];
    ss[t] = v * att_src[t];
    sd[t] = v * att_dst[t];
    __syncthreads();
    if ((t & 127) < 64) { ss[t] += ss[t + 64]; sd[t] += sd[t + 64]; }
    __syncthreads();
    float s2 = ss[t], d2 = sd[t];
#pragma unroll
    for (int off = 32; off > 0; off >>= 1) {
        s2 += __shfl_down(s2, off);
        d2 += __shfl_down(d2, off);
    }
    if ((t & 127) == 0) {
        int g = t >> 7;
        a_src[n * HEADS + g] = s2;
        a_dst[n * HEADS + g] = d2;
    }
}

// ---------------- CSR build ----------------
__global__ void k_deg(const int* __restrict__ ei, int* __restrict__ deg) {
    int e = blockIdx.x * blockDim.x + threadIdx.x;
    if (e >= N_EDGES) return;
    atomicAdd(&deg[ei[N_EDGES + e]], 1);
}

// one-block exclusive scan over deg[50000] -> offs[50001]
#define SCAN_T 1024
#define PER_T  49    // ceil(50000/1024)
__global__ __launch_bounds__(SCAN_T) void k_scan(const int* __restrict__ deg,
                                                 int* __restrict__ offs) {
    __shared__ int sums[SCAN_T];
    const int t = threadIdx.x;
    const int base = t * PER_T;
    int s = 0;
    for (int i = 0; i < PER_T; ++i) {
        int idx = base + i;
        if (idx < N_NODES) s += deg[idx];
    }
    sums[t] = s;
    __syncthreads();
    for (int off = 1; off < SCAN_T; off <<= 1) {
        int v = (t >= off) ? sums[t - off] : 0;
        __syncthreads();
        sums[t] += v;
        __syncthreads();
    }
    int run = sums[t] - s;               // exclusive base for this thread
    for (int i = 0; i < PER_T; ++i) {
        int idx = base + i;
        if (idx < N_NODES) { offs[idx] = run; run += deg[idx]; }
    }
    if (t == SCAN_T - 1) offs[N_NODES] = sums[SCAN_T - 1];
}

__global__ void k_fill(const int* __restrict__ ei,
                       const int* __restrict__ offs,
                       int* __restrict__ cur,
                       int* __restrict__ csr) {
    int e = blockIdx.x * blockDim.x + threadIdx.x;
    if (e >= N_EDGES) return;
    int s = ei[e];
    int d = ei[N_EDGES + e];
    int pos = atomicAdd(&cur[d], 1);
    csr[offs[d] + pos] = s;
}

// ---------------- K5: per-node gather (softmax fused, no atomics) ----------------
// 128 threads/block, one block per dst node; thread owns 4 channels (float4).
__global__ __launch_bounds__(128) void k_gather(const int* __restrict__ offs,
                                                const int* __restrict__ csr,
                                                const float* __restrict__ h,
                                                const float* __restrict__ a_src,
                                                const float* __restrict__ a_dst,
                                                const float* __restrict__ bias,
                                                float* __restrict__ out) {
    const int n = blockIdx.x;
    const int t = threadIdx.x;           // 0..127
    const int head = t >> 5;             // 4 channels/thread -> head = (4t)>>7
    const float4* h4 = (const float4*)h;

    const float ad = a_dst[n * HEADS + head];

    // self loop
    float e0 = a_src[n * HEADS + head] + ad;
    e0 = e0 > 0.f ? e0 : NEG_SLOPE * e0;
    float ex = __expf(e0);
    float4 hv = h4[(size_t)n * 128 + t];
    float4 acc;
    acc.x = ex * hv.x; acc.y = ex * hv.y; acc.z = ex * hv.z; acc.w = ex * hv.w;
    float den = ex;

    const int beg = offs[n], end = offs[n + 1];
    for (int i = beg; i < end; ++i) {
        int s = csr[i];
        float e = a_src[s * HEADS + head] + ad;
        e = e > 0.f ? e : NEG_SLOPE * e;
        float w = __expf(e);
        float4 v = h4[(size_t)s * 128 + t];
        acc.x += w * v.x; acc.y += w * v.y; acc.z += w * v.z; acc.w += w * v.w;
        den += w;
    }

    float inv = 1.f / den;
    float4 b = ((const float4*)bias)[t];
    float4 o;
    o.x = acc.x * inv + b.x; o.y = acc.y * inv + b.y;
    o.z = acc.z * inv + b.z; o.w = acc.w * inv + b.w;
    ((float4*)out)[(size_t)n * 128 + t] = o;
}

extern "C" void kernel_launch(void* const* d_in, const int* in_sizes, int n_in,
                              void* d_out, int out_size, void* d_ws, size_t ws_size,
                              hipStream_t stream) {
    const float* x       = (const float*)d_in[0];
    const int*   ei      = (const int*)  d_in[1];   // harness delivers int32
    const float* W       = (const float*)d_in[2];
    const float* att_src = (const float*)d_in[3];
    const float* att_dst = (const float*)d_in[4];
    const float* bias    = (const float*)d_in[5];
    float* out = (float*)d_out;

    float* ws     = (float*)d_ws;
    float* h      = ws;                                   // 25,600,000 f
    float* a_src  = h     + (size_t)N_NODES * HC;         // 200,000 f
    float* a_dst  = a_src + N_NODES * HEADS;              // 200,000 f
    int*   deg    = (int*)(a_dst + N_NODES * HEADS);      // 50,000 i
    int*   cur    = deg  + N_NODES;                       // 50,000 i
    int*   offs   = cur  + N_NODES;                       // 50,001 i
    int*   csr    = offs + N_NODES + 1;                   // 400,000 i

    // deg and cur are contiguous -> one memset
    hipMemsetAsync(deg, 0, 2 * N_NODES * sizeof(int), stream);

    k_gemm<<<(N_NODES + 31) / 32, 256, 0, stream>>>(x, W, h);
    k_att <<<N_NODES, 512, 0, stream>>>(h, att_src, att_dst, a_src, a_dst);
    k_deg <<<(N_EDGES + 255) / 256, 256, 0, stream>>>(ei, deg);
    k_scan<<<1, SCAN_T, 0, stream>>>(deg, offs);
    k_fill<<<(N_EDGES + 255) / 256, 256, 0, stream>>>(ei, offs, cur, csr);
    k_gather<<<N_NODES, 128, 0, stream>>>(offs, csr, h, a_src, a_dst, bias, out);
}

// Round 5
// 427.475 us; speedup vs baseline: 2.5843x; 1.3327x over previous
//
#include <hip/hip_runtime.h>
#include <math.h>

#define N_NODES 50000
#define N_EDGES 400000
#define HEADS 4
#define CH 128
#define HC 512                        // HEADS*CH
#define NEG_SLOPE 0.2f

typedef float f32x4 __attribute__((ext_vector_type(4)));
typedef short bf16x8 __attribute__((ext_vector_type(8)));

__device__ inline unsigned short f2bf(float f) {
    unsigned int u = __float_as_uint(f);
    unsigned int r = (u + 0x7FFFu + ((u >> 16) & 1u)) >> 16;   // RNE
    return (unsigned short)r;
}
__device__ inline float bf2f(unsigned short u) {
    return __uint_as_float(((unsigned int)u) << 16);
}

// ---------------- K0: W fp32 -> bf16, pre-swizzled into MFMA B-fragment order ----------------
// B-frag for mfma_f32_16x16x32_bf16: lane holds B[k0 + (lane>>4)*8 + j][n0 + (lane&15)], j=0..7.
// Wsw[((kt*32 + nt)*64 + lane)*8 + j], kt=k/32, nt=n/16.
__global__ void k_cast_w(const float* __restrict__ W, unsigned short* __restrict__ Wsw) {
    int i = blockIdx.x * 256 + threadIdx.x;
    if (i >= 128 * HC) return;
    int k = i >> 9, n = i & 511;
    int kt = k >> 5, kk = k & 31;
    int nt = n >> 4, nn = n & 15;
    int lane = ((kk >> 3) << 4) | nn;
    int j = kk & 7;
    Wsw[((size_t)(kt * 32 + nt) * 64 + lane) * 8 + j] = f2bf(W[i]);
}

// ---------------- K1: h = x @ W via bf16 MFMA (fp32 accumulate), h stored bf16 ----------------
// 256 threads = 4 waves; 32 rows/block; wave w owns N-range [w*128, w*128+128).
#define AP 136          // A-tile row pitch (128 + 8 pad)
#define OP 520          // out-stage row pitch (512 + 8 pad)
__global__ __launch_bounds__(256) void k_gemm(const float* __restrict__ x,
                                              const unsigned short* __restrict__ Wsw,
                                              unsigned short* __restrict__ h) {
    __shared__ unsigned short lds[32 * OP];       // 33,280 B; A-tile [32][AP] overlays front
    const int r0  = blockIdx.x * 32;
    const int tid = threadIdx.x;

    // stage A (32x128 fp32 -> bf16 LDS), coalesced float4 loads
    {
        const float4* x4 = (const float4*)x;
#pragma unroll
        for (int i = 0; i < 4; ++i) {
            int idx  = i * 256 + tid;             // float4 index, 1024 total
            int row  = idx >> 5;
            int c4   = idx & 31;
            int grow = r0 + row;
            float4 v;
            if (grow < N_NODES) v = x4[(size_t)grow * 32 + c4];
            else { v.x = v.y = v.z = v.w = 0.f; }
            ushort4 b;
            b.x = f2bf(v.x); b.y = f2bf(v.y); b.z = f2bf(v.z); b.w = f2bf(v.w);
            *(ushort4*)&lds[row * AP + c4 * 4] = b;
        }
    }
    __syncthreads();

    const int wave = tid >> 6;
    const int lane = tid & 63;
    const int mrow = lane & 15;
    const int kgrp = lane >> 4;
    const int ntg0 = wave * 8;                    // wave's first 16-col tile (n0 = wave*128)

    f32x4 acc[2][8];
#pragma unroll
    for (int mt = 0; mt < 2; ++mt)
#pragma unroll
        for (int nt = 0; nt < 8; ++nt) acc[mt][nt] = (f32x4)(0.f);

#pragma unroll
    for (int kt = 0; kt < 4; ++kt) {
        bf16x8 a0 = *(const bf16x8*)&lds[mrow        * AP + kt * 32 + kgrp * 8];
        bf16x8 a1 = *(const bf16x8*)&lds[(16 + mrow) * AP + kt * 32 + kgrp * 8];
#pragma unroll
        for (int nt = 0; nt < 8; ++nt) {
            bf16x8 b = *(const bf16x8*)&Wsw[((size_t)(kt * 32 + ntg0 + nt) * 64 + lane) * 8];
            acc[0][nt] = __builtin_amdgcn_mfma_f32_16x16x32_bf16(a0, b, acc[0][nt], 0, 0, 0);
            acc[1][nt] = __builtin_amdgcn_mfma_f32_16x16x32_bf16(a1, b, acc[1][nt], 0, 0, 0);
        }
    }

    __syncthreads();                              // A-tile dead; reuse LDS as out-stage
    // C/D mapping: col = lane&15, row = (lane>>4)*4 + r
#pragma unroll
    for (int mt = 0; mt < 2; ++mt)
#pragma unroll
        for (int nt = 0; nt < 8; ++nt)
#pragma unroll
            for (int r = 0; r < 4; ++r) {
                int row = mt * 16 + kgrp * 4 + r;
                int col = wave * 128 + nt * 16 + mrow;
                lds[row * OP + col] = f2bf(acc[mt][nt][r]);
            }
    __syncthreads();

    // coalesced bf16 store: 32 rows x 512 = 2048 ushort8 chunks
#pragma unroll
    for (int i = 0; i < 8; ++i) {
        int idx  = i * 256 + tid;                 // ushort8 chunk index
        int row  = idx >> 6;                      // 64 chunks per row
        int c    = idx & 63;
        int grow = r0 + row;
        if (grow < N_NODES) {
            ushort4 lo = *(ushort4*)&lds[row * OP + c * 8];
            ushort4 hi = *(ushort4*)&lds[row * OP + c * 8 + 4];
            *(ushort4*)&h[(size_t)grow * HC + c * 8]     = lo;
            *(ushort4*)&h[(size_t)grow * HC + c * 8 + 4] = hi;
        }
    }
}

// ---------------- K2: a_src/a_dst = <h, att> per (node, head), bf16 h ----------------
__global__ __launch_bounds__(512) void k_att(const unsigned short* __restrict__ h,
                                             const float* __restrict__ att_src,
                                             const float* __restrict__ att_dst,
                                             float* __restrict__ a_src,
                                             float* __restrict__ a_dst) {
    __shared__ float ss[512];
    __shared__ float sd[512];
    const int n = blockIdx.x;
    const int t = threadIdx.x;
    float v = bf2f(h[(size_t)n * HC + t]);
    ss[t] = v * att_src[t];
    sd[t] = v * att_dst[t];
    __syncthreads();
    if ((t & 127) < 64) { ss[t] += ss[t + 64]; sd[t] += sd[t + 64]; }
    __syncthreads();
    float s2 = ss[t], d2 = sd[t];
#pragma unroll
    for (int off = 32; off > 0; off >>= 1) {
        s2 += __shfl_down(s2, off);
        d2 += __shfl_down(d2, off);
    }
    if ((t & 127) == 0) {
        int g = t >> 7;
        a_src[n * HEADS + g] = s2;
        a_dst[n * HEADS + g] = d2;
    }
}

// ---------------- CSR build ----------------
__global__ void k_deg(const int* __restrict__ ei, int* __restrict__ deg) {
    int e = blockIdx.x * blockDim.x + threadIdx.x;
    if (e >= N_EDGES) return;
    atomicAdd(&deg[ei[N_EDGES + e]], 1);
}

#define SCAN_T 1024
#define PER_T  49
__global__ __launch_bounds__(SCAN_T) void k_scan(const int* __restrict__ deg,
                                                 int* __restrict__ offs) {
    __shared__ int sums[SCAN_T];
    const int t = threadIdx.x;
    const int base = t * PER_T;
    int s = 0;
    for (int i = 0; i < PER_T; ++i) {
        int idx = base + i;
        if (idx < N_NODES) s += deg[idx];
    }
    sums[t] = s;
    __syncthreads();
    for (int off = 1; off < SCAN_T; off <<= 1) {
        int v = (t >= off) ? sums[t - off] : 0;
        __syncthreads();
        sums[t] += v;
        __syncthreads();
    }
    int run = sums[t] - s;
    for (int i = 0; i < PER_T; ++i) {
        int idx = base + i;
        if (idx < N_NODES) { offs[idx] = run; run += deg[idx]; }
    }
    if (t == SCAN_T - 1) offs[N_NODES] = sums[SCAN_T - 1];
}

__global__ void k_fill(const int* __restrict__ ei,
                       const int* __restrict__ offs,
                       int* __restrict__ cur,
                       int* __restrict__ csr) {
    int e = blockIdx.x * blockDim.x + threadIdx.x;
    if (e >= N_EDGES) return;
    int s = ei[e];
    int d = ei[N_EDGES + e];
    int pos = atomicAdd(&cur[d], 1);
    csr[offs[d] + pos] = s;
}

// ---------------- K5: per-node gather (softmax fused), bf16 h ----------------
// 128 threads/block; thread owns 4 channels (8 B = ushort4 per edge).
__global__ __launch_bounds__(128) void k_gather(const int* __restrict__ offs,
                                                const int* __restrict__ csr,
                                                const unsigned short* __restrict__ h,
                                                const float* __restrict__ a_src,
                                                const float* __restrict__ a_dst,
                                                const float* __restrict__ bias,
                                                float* __restrict__ out) {
    const int n = blockIdx.x;
    const int t = threadIdx.x;           // 0..127
    const int head = t >> 5;
    const int c0 = t * 4;

    const float ad = a_dst[n * HEADS + head];

    float e0 = a_src[n * HEADS + head] + ad;
    e0 = e0 > 0.f ? e0 : NEG_SLOPE * e0;
    float ex = __expf(e0);
    ushort4 hv = *(const ushort4*)&h[(size_t)n * HC + c0];
    float4 acc;
    acc.x = ex * bf2f(hv.x); acc.y = ex * bf2f(hv.y);
    acc.z = ex * bf2f(hv.z); acc.w = ex * bf2f(hv.w);
    float den = ex;

    const int beg = offs[n], end = offs[n + 1];
    for (int i = beg; i < end; ++i) {
        int s = csr[i];
        float e = a_src[s * HEADS + head] + ad;
        e = e > 0.f ? e : NEG_SLOPE * e;
        float w = __expf(e);
        ushort4 v = *(const ushort4*)&h[(size_t)s * HC + c0];
        acc.x += w * bf2f(v.x); acc.y += w * bf2f(v.y);
        acc.z += w * bf2f(v.z); acc.w += w * bf2f(v.w);
        den += w;
    }

    float inv = 1.f / den;
    float4 b = ((const float4*)bias)[t];
    float4 o;
    o.x = acc.x * inv + b.x; o.y = acc.y * inv + b.y;
    o.z = acc.z * inv + b.z; o.w = acc.w * inv + b.w;
    ((float4*)out)[(size_t)n * 128 + t] = o;
}

extern "C" void kernel_launch(void* const* d_in, const int* in_sizes, int n_in,
                              void* d_out, int out_size, void* d_ws, size_t ws_size,
                              hipStream_t stream) {
    const float* x       = (const float*)d_in[0];
    const int*   ei      = (const int*)  d_in[1];   // harness delivers int32
    const float* W       = (const float*)d_in[2];
    const float* att_src = (const float*)d_in[3];
    const float* att_dst = (const float*)d_in[4];
    const float* bias    = (const float*)d_in[5];
    float* out = (float*)d_out;

    unsigned short* h   = (unsigned short*)d_ws;                  // 25,600,000 u16 (51.2 MB)
    unsigned short* Wsw = h + (size_t)N_NODES * HC;               // 65,536 u16
    float* a_src = (float*)(Wsw + 128 * HC);                      // 200,000 f
    float* a_dst = a_src + N_NODES * HEADS;                       // 200,000 f
    int*   deg   = (int*)(a_dst + N_NODES * HEADS);               // 50,000 i
    int*   cur   = deg  + N_NODES;                                // 50,000 i
    int*   offs  = cur  + N_NODES;                                // 50,001 i
    int*   csr   = offs + N_NODES + 1;                            // 400,000 i

    hipMemsetAsync(deg, 0, 2 * N_NODES * sizeof(int), stream);

    k_cast_w<<<(128 * HC + 255) / 256, 256, 0, stream>>>(W, Wsw);
    k_gemm  <<<(N_NODES + 31) / 32, 256, 0, stream>>>(x, Wsw, h);
    k_att   <<<N_NODES, 512, 0, stream>>>(h, att_src, att_dst, a_src, a_dst);
    k_deg   <<<(N_EDGES + 255) / 256, 256, 0, stream>>>(ei, deg);
    k_scan  <<<1, SCAN_T, 0, stream>>>(deg, offs);
    k_fill  <<<(N_EDGES + 255) / 256, 256, 0, stream>>>(ei, offs, cur, csr);
    k_gather<<<N_NODES, 128, 0, stream>>>(offs, csr, h, a_src, a_dst, bias, out);
}

// Round 6
// 341.087 us; speedup vs baseline: 3.2389x; 1.2533x over previous
//
#include <hip/hip_runtime.h>
#include <math.h>

#define N_NODES 50000
#define N_EDGES 400000
#define HEADS 4
#define CH 128
#define HC 512                        // HEADS*CH
#define NEG_SLOPE 0.2f

typedef float f32x4 __attribute__((ext_vector_type(4)));
typedef short bf16x8 __attribute__((ext_vector_type(8)));

__device__ inline unsigned short f2bf(float f) {
    unsigned int u = __float_as_uint(f);
    unsigned int r = (u + 0x7FFFu + ((u >> 16) & 1u)) >> 16;   // RNE
    return (unsigned short)r;
}
__device__ inline float bf2f(unsigned short u) {
    return __uint_as_float(((unsigned int)u) << 16);
}

// ---------------- K0: W fp32 -> bf16, pre-swizzled into MFMA B-fragment order ----------------
// B-frag for mfma_f32_16x16x32_bf16: lane holds B[k0 + (lane>>4)*8 + j][n0 + (lane&15)], j=0..7.
// Wsw[((kt*32 + nt)*64 + lane)*8 + j], kt=k/32, nt=n/16.
__global__ void k_cast_w(const float* __restrict__ W, unsigned short* __restrict__ Wsw) {
    int i = blockIdx.x * 256 + threadIdx.x;
    if (i >= 128 * HC) return;
    int k = i >> 9, n = i & 511;
    int kt = k >> 5, kk = k & 31;
    int nt = n >> 4, nn = n & 15;
    int lane = ((kk >> 3) << 4) | nn;
    int j = kk & 7;
    Wsw[((size_t)(kt * 32 + nt) * 64 + lane) * 8 + j] = f2bf(W[i]);
}

// ---------------- K1: h = x @ W via bf16 MFMA (fp32 accumulate), h stored bf16 ----------------
// 256 threads = 4 waves; 32 rows/block; wave w owns N-range [w*128, w*128+128).
#define AP 136          // A-tile row pitch (128 + 8 pad)
#define OP 520          // out-stage row pitch (512 + 8 pad)
__global__ __launch_bounds__(256) void k_gemm(const float* __restrict__ x,
                                              const unsigned short* __restrict__ Wsw,
                                              unsigned short* __restrict__ h) {
    __shared__ unsigned short lds[32 * OP];       // 33,280 B; A-tile [32][AP] overlays front
    const int r0  = blockIdx.x * 32;
    const int tid = threadIdx.x;

    // stage A (32x128 fp32 -> bf16 LDS), coalesced float4 loads
    {
        const float4* x4 = (const float4*)x;
#pragma unroll
        for (int i = 0; i < 4; ++i) {
            int idx  = i * 256 + tid;             // float4 index, 1024 total
            int row  = idx >> 5;
            int c4   = idx & 31;
            int grow = r0 + row;
            float4 v;
            if (grow < N_NODES) v = x4[(size_t)grow * 32 + c4];
            else { v.x = v.y = v.z = v.w = 0.f; }
            ushort4 b;
            b.x = f2bf(v.x); b.y = f2bf(v.y); b.z = f2bf(v.z); b.w = f2bf(v.w);
            *(ushort4*)&lds[row * AP + c4 * 4] = b;
        }
    }
    __syncthreads();

    const int wave = tid >> 6;
    const int lane = tid & 63;
    const int mrow = lane & 15;
    const int kgrp = lane >> 4;
    const int ntg0 = wave * 8;                    // wave's first 16-col tile (n0 = wave*128)

    f32x4 acc[2][8];
#pragma unroll
    for (int mt = 0; mt < 2; ++mt)
#pragma unroll
        for (int nt = 0; nt < 8; ++nt) acc[mt][nt] = (f32x4)(0.f);

#pragma unroll
    for (int kt = 0; kt < 4; ++kt) {
        bf16x8 a0 = *(const bf16x8*)&lds[mrow        * AP + kt * 32 + kgrp * 8];
        bf16x8 a1 = *(const bf16x8*)&lds[(16 + mrow) * AP + kt * 32 + kgrp * 8];
#pragma unroll
        for (int nt = 0; nt < 8; ++nt) {
            bf16x8 b = *(const bf16x8*)&Wsw[((size_t)(kt * 32 + ntg0 + nt) * 64 + lane) * 8];
            acc[0][nt] = __builtin_amdgcn_mfma_f32_16x16x32_bf16(a0, b, acc[0][nt], 0, 0, 0);
            acc[1][nt] = __builtin_amdgcn_mfma_f32_16x16x32_bf16(a1, b, acc[1][nt], 0, 0, 0);
        }
    }

    __syncthreads();                              // A-tile dead; reuse LDS as out-stage
    // C/D mapping: col = lane&15, row = (lane>>4)*4 + r
#pragma unroll
    for (int mt = 0; mt < 2; ++mt)
#pragma unroll
        for (int nt = 0; nt < 8; ++nt)
#pragma unroll
            for (int r = 0; r < 4; ++r) {
                int row = mt * 16 + kgrp * 4 + r;
                int col = wave * 128 + nt * 16 + mrow;
                lds[row * OP + col] = f2bf(acc[mt][nt][r]);
            }
    __syncthreads();

    // coalesced bf16 store: 32 rows x 512 = 2048 ushort8 chunks
#pragma unroll
    for (int i = 0; i < 8; ++i) {
        int idx  = i * 256 + tid;                 // ushort8 chunk index
        int row  = idx >> 6;                      // 64 chunks per row
        int c    = idx & 63;
        int grow = r0 + row;
        if (grow < N_NODES) {
            ushort4 lo = *(ushort4*)&lds[row * OP + c * 8];
            ushort4 hi = *(ushort4*)&lds[row * OP + c * 8 + 4];
            *(ushort4*)&h[(size_t)grow * HC + c * 8]     = lo;
            *(ushort4*)&h[(size_t)grow * HC + c * 8 + 4] = hi;
        }
    }
}

// ---------------- K2: a_src/a_dst = <h, att> per (node, head), bf16 h ----------------
__global__ __launch_bounds__(512) void k_att(const unsigned short* __restrict__ h,
                                             const float* __restrict__ att_src,
                                             const float* __restrict__ att_dst,
                                             float* __restrict__ a_src,
                                             float* __restrict__ a_dst) {
    __shared__ float ss[512];
    __shared__ float sd[512];
    const int n = blockIdx.x;
    const int t = threadIdx.x;
    float v = bf2f(h[(size_t)n * HC + t]);
    ss[t] = v * att_src[t];
    sd[t] = v * att_dst[t];
    __syncthreads();
    if ((t & 127) < 64) { ss[t] += ss[t + 64]; sd[t] += sd[t + 64]; }
    __syncthreads();
    float s2 = ss[t], d2 = sd[t];
#pragma unroll
    for (int off = 32; off > 0; off >>= 1) {
        s2 += __shfl_down(s2, off);
        d2 += __shfl_down(d2, off);
    }
    if ((t & 127) == 0) {
        int g = t >> 7;
        a_src[n * HEADS + g] = s2;
        a_dst[n * HEADS + g] = d2;
    }
}

// ---------------- CSR build ----------------
__global__ void k_deg(const int* __restrict__ ei, int* __restrict__ deg) {
    int e = blockIdx.x * blockDim.x + threadIdx.x;
    if (e >= N_EDGES) return;
    atomicAdd(&deg[ei[N_EDGES + e]], 1);
}

// ---- device-wide exclusive scan of deg[50000] -> offs[], 3 passes ----
#define SCB 256
#define SNB ((N_NODES + SCB - 1) / SCB)    // 196 blocks

__device__ inline int block_excl_scan(int v, int t, int* total_out) {
    // 256 threads = 4 waves: shuffle inclusive scan per wave + LDS combine
    __shared__ int wbase[4];
    const int lane = t & 63, w = t >> 6;
    int inc = v;
#pragma unroll
    for (int off = 1; off < 64; off <<= 1) {
        int u = __shfl_up(inc, off);
        if (lane >= off) inc += u;
    }
    if (lane == 63) wbase[w] = inc;
    __syncthreads();
    if (t == 0) {
        int r = 0;
#pragma unroll
        for (int i = 0; i < 4; ++i) { int x = wbase[i]; wbase[i] = r; r += x; }
    }
    __syncthreads();
    int excl = inc - v + wbase[w];
    if (total_out && t == SCB - 1) *total_out = excl + v;
    __syncthreads();
    return excl;
}

__global__ __launch_bounds__(SCB) void k_scan1(const int* __restrict__ deg,
                                               int* __restrict__ offs,
                                               int* __restrict__ part) {
    __shared__ int tot;
    int idx = blockIdx.x * SCB + threadIdx.x;
    int v = (idx < N_NODES) ? deg[idx] : 0;
    int excl = block_excl_scan(v, threadIdx.x, &tot);
    if (idx < N_NODES) offs[idx] = excl;
    if (threadIdx.x == SCB - 1) part[blockIdx.x] = tot;
}

__global__ __launch_bounds__(SCB) void k_scan2(int* __restrict__ part,
                                               int* __restrict__ offs) {
    __shared__ int tot;
    int t = threadIdx.x;
    int v = (t < SNB) ? part[t] : 0;
    int excl = block_excl_scan(v, t, &tot);
    if (t < SNB) part[t] = excl;
    if (t == SCB - 1) offs[N_NODES] = tot;     // == N_EDGES
}

__global__ __launch_bounds__(SCB) void k_scan3(int* __restrict__ offs,
                                               const int* __restrict__ part) {
    int idx = blockIdx.x * SCB + threadIdx.x;
    if (idx < N_NODES) offs[idx] += part[blockIdx.x];
}

__global__ void k_fill(const int* __restrict__ ei,
                       const int* __restrict__ offs,
                       int* __restrict__ cur,
                       int* __restrict__ csr) {
    int e = blockIdx.x * blockDim.x + threadIdx.x;
    if (e >= N_EDGES) return;
    int s = ei[e];
    int d = ei[N_EDGES + e];
    int pos = atomicAdd(&cur[d], 1);
    csr[offs[d] + pos] = s;
}

// ---------------- K5: per-node gather (softmax fused), bf16 h ----------------
// 128 threads/block; thread owns 4 channels (8 B = ushort4 per edge).
__global__ __launch_bounds__(128) void k_gather(const int* __restrict__ offs,
                                                const int* __restrict__ csr,
                                                const unsigned short* __restrict__ h,
                                                const float* __restrict__ a_src,
                                                const float* __restrict__ a_dst,
                                                const float* __restrict__ bias,
                                                float* __restrict__ out) {
    const int n = blockIdx.x;
    const int t = threadIdx.x;           // 0..127
    const int head = t >> 5;
    const int c0 = t * 4;

    const float ad = a_dst[n * HEADS + head];

    float e0 = a_src[n * HEADS + head] + ad;
    e0 = e0 > 0.f ? e0 : NEG_SLOPE * e0;
    float ex = __expf(e0);
    ushort4 hv = *(const ushort4*)&h[(size_t)n * HC + c0];
    float4 acc;
    acc.x = ex * bf2f(hv.x); acc.y = ex * bf2f(hv.y);
    acc.z = ex * bf2f(hv.z); acc.w = ex * bf2f(hv.w);
    float den = ex;

    const int beg = offs[n], end = offs[n + 1];
    for (int i = beg; i < end; ++i) {
        int s = csr[i];
        float e = a_src[s * HEADS + head] + ad;
        e = e > 0.f ? e : NEG_SLOPE * e;
        float w = __expf(e);
        ushort4 v = *(const ushort4*)&h[(size_t)s * HC + c0];
        acc.x += w * bf2f(v.x); acc.y += w * bf2f(v.y);
        acc.z += w * bf2f(v.z); acc.w += w * bf2f(v.w);
        den += w;
    }

    float inv = 1.f / den;
    float4 b = ((const float4*)bias)[t];
    float4 o;
    o.x = acc.x * inv + b.x; o.y = acc.y * inv + b.y;
    o.z = acc.z * inv + b.z; o.w = acc.w * inv + b.w;
    ((float4*)out)[(size_t)n * 128 + t] = o;
}

extern "C" void kernel_launch(void* const* d_in, const int* in_sizes, int n_in,
                              void* d_out, int out_size, void* d_ws, size_t ws_size,
                              hipStream_t stream) {
    const float* x       = (const float*)d_in[0];
    const int*   ei      = (const int*)  d_in[1];   // harness delivers int32
    const float* W       = (const float*)d_in[2];
    const float* att_src = (const float*)d_in[3];
    const float* att_dst = (const float*)d_in[4];
    const float* bias    = (const float*)d_in[5];
    float* out = (float*)d_out;

    unsigned short* h   = (unsigned short*)d_ws;                  // 25,600,000 u16 (51.2 MB)
    unsigned short* Wsw = h + (size_t)N_NODES * HC;               // 65,536 u16
    float* a_src = (float*)(Wsw + 128 * HC);                      // 200,000 f
    float* a_dst = a_src + N_NODES * HEADS;                       // 200,000 f
    int*   deg   = (int*)(a_dst + N_NODES * HEADS);               // 50,000 i
    int*   cur   = deg  + N_NODES;                                // 50,000 i
    int*   offs  = cur  + N_NODES;                                // 50,001 i
    int*   part  = offs + N_NODES + 1;                            // 256 i
    int*   csr   = part + 256;                                    // 400,000 i

    hipMemsetAsync(deg, 0, 2 * N_NODES * sizeof(int), stream);

    k_cast_w<<<(128 * HC + 255) / 256, 256, 0, stream>>>(W, Wsw);
    k_gemm  <<<(N_NODES + 31) / 32, 256, 0, stream>>>(x, Wsw, h);
    k_att   <<<N_NODES, 512, 0, stream>>>(h, att_src, att_dst, a_src, a_dst);
    k_deg   <<<(N_EDGES + 255) / 256, 256, 0, stream>>>(ei, deg);
    k_scan1 <<<SNB, SCB, 0, stream>>>(deg, offs, part);
    k_scan2 <<<1, SCB, 0, stream>>>(part, offs);
    k_scan3 <<<SNB, SCB, 0, stream>>>(offs, part);
    k_fill  <<<(N_EDGES + 255) / 256, 256, 0, stream>>>(ei, offs, cur, csr);
    k_gather<<<N_NODES, 128, 0, stream>>>(offs, csr, h, a_src, a_dst, bias, out);
}